// Round 19
// baseline (1052.689 us; speedup 1.0000x reference)
//
#include <hip/hip_runtime.h>
#include <cstdint>
#include <cstddef>

#define B_  16
#define N_  4096
#define M_  512
#define KNB 16
#define P_  (B_ * M_)
#define ROWS_ (B_ * M_ * KNB)   // 131072

typedef unsigned short u16;
typedef unsigned long long u64;
typedef __attribute__((ext_vector_type(4))) unsigned int u32x4;
typedef __attribute__((ext_vector_type(8))) short short8;
typedef __attribute__((ext_vector_type(4))) float f32x4v;

__device__ inline u16 f2bf(float f) {
  union { float f; unsigned u; } x; x.f = f;
  unsigned r = x.u + 0x7fffu + ((x.u >> 16) & 1u);
  return (u16)(r >> 16);
}
__device__ inline float bf2f(u16 h) {
  union { unsigned u; float f; } x; x.u = ((unsigned)h) << 16;
  return x.f;
}

// ---------------------------------------------------------------------------
// Packed-u64 wave reductions via DPP (row_shr 1/2/4/8 + row_bcast 15/31).
// ---------------------------------------------------------------------------
__device__ inline u64 wave_max_u64(u64 k) {
#define STEP64MAX(ctrl)                                                               \
  {                                                                                   \
    unsigned olo = (unsigned)__builtin_amdgcn_update_dpp(0, (int)(unsigned)k, ctrl, 0xf, 0xf, false); \
    unsigned ohi = (unsigned)__builtin_amdgcn_update_dpp(0, (int)(unsigned)(k >> 32), ctrl, 0xf, 0xf, false); \
    u64 o = ((u64)ohi << 32) | olo;                                                   \
    k = o > k ? o : k;                                                                \
  }
  STEP64MAX(0x111) STEP64MAX(0x112) STEP64MAX(0x114) STEP64MAX(0x118)
  STEP64MAX(0x142) STEP64MAX(0x143)
#undef STEP64MAX
  unsigned rlo = (unsigned)__builtin_amdgcn_readlane((int)(unsigned)k, 63);
  unsigned rhi = (unsigned)__builtin_amdgcn_readlane((int)(unsigned)(k >> 32), 63);
  return ((u64)rhi << 32) | rlo;
}
__device__ inline u64 wave_min_u64(u64 k) {
#define STEP64MIN(ctrl)                                                               \
  {                                                                                   \
    unsigned olo = (unsigned)__builtin_amdgcn_update_dpp(-1, (int)(unsigned)k, ctrl, 0xf, 0xf, false); \
    unsigned ohi = (unsigned)__builtin_amdgcn_update_dpp(-1, (int)(unsigned)(k >> 32), ctrl, 0xf, 0xf, false); \
    u64 o = ((u64)ohi << 32) | olo;                                                   \
    k = o < k ? o : k;                                                                \
  }
  STEP64MIN(0x111) STEP64MIN(0x112) STEP64MIN(0x114) STEP64MIN(0x118)
  STEP64MIN(0x142) STEP64MIN(0x143)
#undef STEP64MIN
  unsigned rlo = (unsigned)__builtin_amdgcn_readlane((int)(unsigned)k, 63);
  unsigned rhi = (unsigned)__builtin_amdgcn_readlane((int)(unsigned)(k >> 32), 63);
  return ((u64)rhi << 32) | rlo;
}

// ---------------------------------------------------------------------------
// FPS: 512 threads, 8 pts/lane. In-lane argmax via f32 value + slot index
// (strict-greater keeps LOWER slot = lower point index, matching the u64-key
// tie rule since p = t + j*512 is monotone in j); u64 key packed ONCE per
// lane, then the r8-verified DPP u64 wave-max + 8-key LDS reduce.
// Distance chain bit-identical to the verified version.
// ---------------------------------------------------------------------------
__global__ __launch_bounds__(512) void fps_kernel(const float* __restrict__ x,
                                                  float* __restrict__ pts) {
  __shared__ float4 xs4[N_];
  __shared__ __align__(16) u64 rv64[2][8];
  const int b = blockIdx.x, t = threadIdx.x, lane = t & 63, w = t >> 6;
  const float* xb = x + (size_t)b * N_ * 3;
  for (int p = t; p < N_; p += 512) {
    const float* s = xb + p * 3;
    xs4[p] = make_float4(s[0], s[1], s[2], 0.f);
  }
  __syncthreads();

  float px[8], py[8], pz[8], dm[8];
#pragma unroll
  for (int j = 0; j < 8; ++j) {
    float4 v = xs4[t + j * 512];
    px[j] = v.x; py[j] = v.y; pz[j] = v.z;
    dm[j] = __builtin_inff();
  }
  float cx = xs4[0].x, cy = xs4[0].y, cz = xs4[0].z;
  if (t == 0) {
    pts[(size_t)b * M_ * 3 + 0] = cx;
    pts[(size_t)b * M_ * 3 + 1] = cy;
    pts[(size_t)b * M_ * 3 + 2] = cz;
  }
  for (int i = 1; i < M_; ++i) {
    float d[8];
#pragma unroll
    for (int j = 0; j < 8; ++j) {
      float dx = px[j] - cx, dy = py[j] - cy, dz = pz[j] - cz;
      float dd = __fmul_rn(dx, dx);
      dd = __fadd_rn(dd, __fmul_rn(dy, dy));
      dd = __fadd_rn(dd, __fmul_rn(dz, dz));
      dd = fminf(dm[j], dd);
      dm[j] = dd;
      d[j] = dd;
    }
    // in-lane f32+index tree: strict-greater takes the higher slot, so equal
    // values keep the lower slot (= lower point index). Monotone j -> p.
    float v4[4]; int j4[4];
#pragma unroll
    for (int j = 0; j < 4; ++j) {
      bool tk = d[j + 4] > d[j];
      v4[j] = tk ? d[j + 4] : d[j];
      j4[j] = tk ? (j + 4) : j;
    }
    float v2[2]; int j2[2];
#pragma unroll
    for (int j = 0; j < 2; ++j) {
      bool tk = (v4[j + 2] > v4[j]) || (v4[j + 2] == v4[j] && j4[j + 2] < j4[j]);
      v2[j] = tk ? v4[j + 2] : v4[j];
      j2[j] = tk ? j4[j + 2] : j4[j];
    }
    bool tk0 = (v2[1] > v2[0]) || (v2[1] == v2[0] && j2[1] < j2[0]);
    float bv = tk0 ? v2[1] : v2[0];
    int bp = t + (tk0 ? j2[1] : j2[0]) * 512;
    u64 kb = ((u64)__float_as_uint(bv) << 32) | (unsigned)(~bp);
    kb = wave_max_u64(kb);

    const int par = i & 1;
    if (lane == 0) rv64[par][w] = kb;
    __syncthreads();
    u32x4 a0 = *(const u32x4*)&rv64[par][0];
    u32x4 a1 = *(const u32x4*)&rv64[par][2];
    u32x4 a2 = *(const u32x4*)&rv64[par][4];
    u32x4 a3 = *(const u32x4*)&rv64[par][6];
    u64 q0 = ((u64)a0[1] << 32) | a0[0];
    u64 q1 = ((u64)a0[3] << 32) | a0[2];
    u64 q2 = ((u64)a1[1] << 32) | a1[0];
    u64 q3 = ((u64)a1[3] << 32) | a1[2];
    u64 q4 = ((u64)a2[1] << 32) | a2[0];
    u64 q5 = ((u64)a2[3] << 32) | a2[2];
    u64 q6 = ((u64)a3[1] << 32) | a3[0];
    u64 q7 = ((u64)a3[3] << 32) | a3[2];
    u64 m0 = q0 > q1 ? q0 : q1;
    u64 m1 = q2 > q3 ? q2 : q3;
    u64 m2 = q4 > q5 ? q4 : q5;
    u64 m3 = q6 > q7 ? q6 : q7;
    u64 n0 = m0 > m1 ? m0 : m1;
    u64 n1 = m2 > m3 ? m2 : m3;
    u64 km = n0 > n1 ? n0 : n1;
    int fi = (int)(~(unsigned)km) & (N_ - 1);
    float4 cc = xs4[fi];
    cx = cc.x; cy = cc.y; cz = cc.z;
    if (t == 0) {
      pts[((size_t)b * M_ + i) * 3 + 0] = cx;
      pts[((size_t)b * M_ + i) * 3 + 1] = cy;
      pts[((size_t)b * M_ + i) * 3 + 2] = cz;
    }
  }
}

// ---------------------------------------------------------------------------
// kNN (r13-verified): 256 threads, ~252 VGPRs, keyed top-16, equality
// invalidation with compile-time indices (no scratch spill).
// ---------------------------------------------------------------------------
template <int C>
__global__ __launch_bounds__(256) void knn_kernel(const float* __restrict__ f,
                                                  int* __restrict__ knn) {
  constexpr int C4 = (C + 3) / 4;
  __shared__ float4 ls4[C4 * 513];
  float* lss = (float*)ls4;
  const int b = blockIdx.x >> 4;
  const int mb = (blockIdx.x & 15) * 32;
  const int t = threadIdx.x, lane = t & 63, w = t >> 6;
  const float* fb = f + (size_t)b * M_ * C;
  if (C & 3) {
    for (int j = t; j < M_; j += 256)
      for (int cc = (C & 3); cc < 4; ++cc)
        lss[((C4 - 1) * 513 + j) * 4 + cc] = 0.f;
  }
  for (int s = t; s < M_ * C; s += 256) {
    int j = s / C, c = s % C;
    lss[((c >> 2) * 513 + j) * 4 + (c & 3)] = fb[s];
  }
  __syncthreads();

  float sqj[8];
#pragma unroll
  for (int jj = 0; jj < 8; ++jj) {
    int j = lane + 64 * jj;
    float a = 0.f;
    for (int c4 = 0; c4 < C4; ++c4) {
      float4 v = ls4[c4 * 513 + j];
      a += v.x * v.x + v.y * v.y + v.z * v.z + v.w * v.w;
    }
    sqj[jj] = a;
  }

  for (int rr = 0; rr < 8; ++rr) {
    const int m = mb + w * 8 + rr;
    float sqm = 0.f;
    for (int c4 = 0; c4 < C4; ++c4) {
      float4 v = ls4[c4 * 513 + m];
      sqm += v.x * v.x + v.y * v.y + v.z * v.z + v.w * v.w;
    }
    float dot[8] = {0.f, 0.f, 0.f, 0.f, 0.f, 0.f, 0.f, 0.f};
    for (int c4 = 0; c4 < C4; ++c4) {
      float4 fm = ls4[c4 * 513 + m];
#pragma unroll
      for (int jj = 0; jj < 8; ++jj) {
        float4 fj = ls4[c4 * 513 + lane + 64 * jj];
        dot[jj] += fm.x * fj.x + fm.y * fj.y + fm.z * fj.z + fm.w * fj.w;
      }
    }
    u64 mk[8];
#pragma unroll
    for (int jj = 0; jj < 8; ++jj) {
      float d = (sqm - 2.f * dot[jj]) + sqj[jj];
      unsigned um = __float_as_uint(d);
      um = (um >> 31) ? ~um : (um | 0x80000000u);   // order-preserving f32->u32
      mk[jj] = ((u64)um << 32) | (unsigned)(lane + 64 * jj);
    }

    int* out = knn + ((size_t)b * M_ + m) * KNB;
    for (int kk = 0; kk < KNB; ++kk) {
      u64 k4[4], k2[2], kb;
#pragma unroll
      for (int jj = 0; jj < 4; ++jj) k4[jj] = mk[jj] < mk[jj + 4] ? mk[jj] : mk[jj + 4];
#pragma unroll
      for (int jj = 0; jj < 2; ++jj) k2[jj] = k4[jj] < k4[jj + 2] ? k4[jj] : k4[jj + 2];
      kb = k2[0] < k2[1] ? k2[0] : k2[1];
      kb = wave_min_u64(kb);
#pragma unroll
      for (int jj = 0; jj < 8; ++jj)
        if (mk[jj] == kb) mk[jj] = ~0ull;          // unique keys -> exact winner
      if (lane == 0) out[kk] = (int)(unsigned)kb;
    }
  }
}

// ---------------------------------------------------------------------------
// Weight prep for pointproj (r17-verified): Wcomb[4D][K32] hi/lo, swizzled.
// ---------------------------------------------------------------------------
__global__ void prep_wqkv(const float* __restrict__ Wq, const float* __restrict__ Wk,
                          const float* __restrict__ Wv, int C, int D, int K32,
                          u16* __restrict__ Wh, u16* __restrict__ Wl) {
  int idx = blockIdx.x * 256 + threadIdx.x;
  if (idx >= 4 * D * K32) return;
  int n = idx / K32, c = idx % K32;
  float wv = 0.f;
  if (c < C) {
    int reg = n / D, d = n % D;
    int twoC = 2 * C;
    if (reg == 0)      wv = Wq[d * twoC + c] - Wk[d * twoC + c];
    else if (reg == 1) wv = (Wq[d * twoC + C + c] - Wk[d * twoC + C + c]) -
                            (Wq[d * twoC + c] - Wk[d * twoC + c]);
    else if (reg == 2) wv = Wv[d * twoC + c];
    else               wv = Wv[d * twoC + C + c] - Wv[d * twoC + c];
  }
  int sw = ((n >> 4) * (K32 >> 3) + (c >> 3)) * 128 + (n & 15) * 8 + (c & 7);
  u16 h = f2bf(wv);
  Wh[sw] = h;
  Wl[sw] = f2bf(wv - bf2f(h));
}

// ---------------------------------------------------------------------------
// pointproj via split-precision MFMA (r17-verified).
// ---------------------------------------------------------------------------
template <int K32>
__global__ __launch_bounds__(256) void pointproj_mfma(
    const float* __restrict__ f, int C, int fourD,
    const u16* __restrict__ Wh, const u16* __restrict__ Wl,
    float* __restrict__ PC) {
  __shared__ u32x4 Ah[4 * 65], Al[4 * 65];
  constexpr int KC = K32 / 8;
  const int t = threadIdx.x, lane = t & 63, w = t >> 6;
  const int r0 = blockIdx.x * 64, n0 = blockIdx.y * 64;
  const int wr = (w >> 1) * 32, wc = (w & 1) * 32;
  const int kch = lane >> 4, lrow = lane & 15;
  const int srow = t >> 2, ss = t & 3;
  f32x4v acc[2][2];
#pragma unroll
  for (int a = 0; a < 2; ++a)
#pragma unroll
    for (int b = 0; b < 2; ++b) acc[a][b] = (f32x4v){0.f, 0.f, 0.f, 0.f};

  const int ldsw = ss * 65 + srow;
  const int ra = kch * 65 + lrow;

#pragma unroll
  for (int k0 = 0; k0 < K32; k0 += 32) {
    float af[8];
#pragma unroll
    for (int i = 0; i < 8; ++i) {
      int c = k0 + ss * 8 + i;
      af[i] = (c < C) ? f[(size_t)(r0 + srow) * C + c] : 0.f;
    }
    u32x4 vah, val;
#pragma unroll
    for (int q = 0; q < 4; ++q) {
      u16 h0 = f2bf(af[2 * q]), h1 = f2bf(af[2 * q + 1]);
      u16 l0 = f2bf(af[2 * q] - bf2f(h0));
      u16 l1 = f2bf(af[2 * q + 1] - bf2f(h1));
      vah[q] = (unsigned)h0 | ((unsigned)h1 << 16);
      val[q] = (unsigned)l0 | ((unsigned)l1 << 16);
    }
    __syncthreads();
    Ah[ldsw] = vah; Al[ldsw] = val;
    __syncthreads();
    union { u32x4 u; short8 s; } ah0, ah1, al0, al1, bh[2], bl[2];
    ah0.u = Ah[ra + wr]; ah1.u = Ah[ra + wr + 16];
    al0.u = Al[ra + wr]; al1.u = Al[ra + wr + 16];
#pragma unroll
    for (int fc = 0; fc < 2; ++fc) {
      size_t bi = (size_t)((((n0 + wc) >> 4) + fc) * KC + (k0 >> 3) + kch) * 128 + lrow * 8;
      bh[fc].u = *(const u32x4*)(Wh + bi);
      bl[fc].u = *(const u32x4*)(Wl + bi);
    }
#pragma unroll
    for (int fc = 0; fc < 2; ++fc) {
      acc[0][fc] = __builtin_amdgcn_mfma_f32_16x16x32_bf16(ah0.s, bh[fc].s, acc[0][fc], 0, 0, 0);
      acc[1][fc] = __builtin_amdgcn_mfma_f32_16x16x32_bf16(ah1.s, bh[fc].s, acc[1][fc], 0, 0, 0);
      acc[0][fc] = __builtin_amdgcn_mfma_f32_16x16x32_bf16(al0.s, bh[fc].s, acc[0][fc], 0, 0, 0);
      acc[1][fc] = __builtin_amdgcn_mfma_f32_16x16x32_bf16(al1.s, bh[fc].s, acc[1][fc], 0, 0, 0);
      acc[0][fc] = __builtin_amdgcn_mfma_f32_16x16x32_bf16(ah0.s, bl[fc].s, acc[0][fc], 0, 0, 0);
      acc[1][fc] = __builtin_amdgcn_mfma_f32_16x16x32_bf16(ah1.s, bl[fc].s, acc[1][fc], 0, 0, 0);
    }
  }

  const int rowb = r0 + wr + kch * 4;
  const int colb = n0 + wc + lrow;
#pragma unroll
  for (int fr = 0; fr < 2; ++fr)
#pragma unroll
    for (int fc = 0; fc < 2; ++fc)
#pragma unroll
      for (int q = 0; q < 4; ++q) {
        int row = rowb + fr * 16 + q;
        int col = colb + fc * 16;
        PC[(size_t)row * fourD + col] = acc[fr][fc][q];
      }
}

// ---------------------------------------------------------------------------
// Weight split + swizzle to MFMA fragment order (P2/A1/A2).
// ---------------------------------------------------------------------------
__global__ void split3_w(const float* __restrict__ Wa, int na, int Ka,
                         const float* __restrict__ Wb, int nb, int Kb,
                         const float* __restrict__ Wc, int nc, int Kc,
                         u16* __restrict__ Ah, u16* __restrict__ Al,
                         u16* __restrict__ Bh, u16* __restrict__ Bl,
                         u16* __restrict__ Ch, u16* __restrict__ Cl) {
  int k = blockIdx.x * 256 + threadIdx.x;
  const float* s; u16 *dh, *dl; int K;
  if (k < na) { s = Wa; dh = Ah; dl = Al; K = Ka; }
  else if ((k -= na) < nb) { s = Wb; dh = Bh; dl = Bl; K = Kb; }
  else if ((k -= nb) < nc) { s = Wc; dh = Ch; dl = Cl; K = Kc; }
  else return;
  int n = k / K, kk = k % K;
  int sw = ((n >> 4) * (K >> 3) + (kk >> 3)) * 128 + (n & 15) * 8 + (kk & 7);
  float v = s[k];
  u16 h = f2bf(v);
  dh[sw] = h;
  dl[sw] = f2bf(v - bf2f(h));
}

// ---------------------------------------------------------------------------
// Fused transformer layer (r15-verified: swizzled weight fragments).
// ---------------------------------------------------------------------------
template <int D, int H, int RB>
__global__ __launch_bounds__(256) void mega_kernel(
    const float* __restrict__ pts, const float* __restrict__ PC,
    const int* __restrict__ idx, const float* __restrict__ P1,
    const u16* __restrict__ P2h, const u16* __restrict__ P2l,
    const u16* __restrict__ A1h, const u16* __restrict__ A1l,
    const u16* __restrict__ A2h, const u16* __restrict__ A2l,
    float* __restrict__ xout) {
  constexpr int WC = D / 32;
  constexpr int HT = (RB == 64) ? 64 : 128;
  constexpr int WCa = HT / 32;
  constexpr int KCD = D / 8;
  constexpr int KCH = H / 8;
  constexpr int NIT = H / HT;
  constexpr int LSTR = RB + 1;
  constexpr int FD = 4 * D;

  __shared__ u32x4 sh_[KCD * LSTR], sl_[KCD * LSTR];
  __shared__ u32x4 xh_[KCD * LSTR], xl_[KCD * LSTR];
  __shared__ float rel4[RB][4];
  __shared__ int   nps[RB];
  __shared__ float P1s[D][4];

  const int t = threadIdx.x, lane = t & 63, w = t >> 6;
  const int kch = lane >> 4, lrow = lane & 15;
  const int r0g = blockIdx.x * RB;
  const int bm0 = r0g >> 4;

  if (t < RB) {
    int gr = r0g + t;
    int bb = gr >> 13;
    int np = bb * M_ + idx[gr];
    int bm = gr >> 4;
    nps[t] = np;
    rel4[t][0] = pts[np * 3 + 0] - pts[bm * 3 + 0];
    rel4[t][1] = pts[np * 3 + 1] - pts[bm * 3 + 1];
    rel4[t][2] = pts[np * 3 + 2] - pts[bm * 3 + 2];
  }
  for (int e = t; e < D * 4; e += 256) {
    int dd = e >> 2, c = e & 3;
    P1s[dd][c] = (c < 3) ? P1[dd * 3 + c] : 0.f;
  }
  __syncthreads();

  u16* xh_u = (u16*)xh_;
  u16* xl_u = (u16*)xl_;
  u16* sh_u = (u16*)sh_;
  u16* sl_u = (u16*)sl_;

  const int wr2 = (w / WC) * 32, wc2 = (w % WC) * 32;

  // u gathered per-fragment into registers
  float u_r[2][2][4];
#pragma unroll
  for (int fr = 0; fr < 2; ++fr)
#pragma unroll
    for (int fc = 0; fc < 2; ++fc)
#pragma unroll
      for (int q = 0; q < 4; ++q) {
        int row = wr2 + fr * 16 + kch * 4 + q;
        int col = wc2 + fc * 16 + lrow;
        int np = nps[row];
        int bm = bm0 + (row >> 4);
        u_r[fr][fc][q] = PC[(size_t)np * FD + col] + PC[(size_t)bm * FD + D + col];
      }

  // h1 build (bf16 hi/lo into LDS)
#pragma unroll
  for (int i = 0; i < RB * D / 256; ++i) {
    int e = t + i * 256;
    int r = e / D, dd = e % D;
    float hh = fmaxf(P1s[dd][0] * rel4[r][0] + P1s[dd][1] * rel4[r][1] +
                     P1s[dd][2] * rel4[r][2], 0.f);
    u16 hi = f2bf(hh), lo = f2bf(hh - bf2f(hi));
    int off = ((dd >> 3) * LSTR + r) * 8 + (dd & 7);
    xh_u[off] = hi; xl_u[off] = lo;
  }
  __syncthreads();

  // phase 2: pe = h1 @ P2^T ; s = u + pe ; pe kept in registers
  f32x4v pe_r[2][2];
  {
    f32x4v pac[2][2];
#pragma unroll
    for (int a = 0; a < 2; ++a)
#pragma unroll
      for (int b = 0; b < 2; ++b) pac[a][b] = (f32x4v){0.f, 0.f, 0.f, 0.f};
#pragma unroll
    for (int k0 = 0; k0 < D; k0 += 32) {
      union { u32x4 u; short8 s; } ah[2], al[2], bh[2], bl[2];
#pragma unroll
      for (int fr = 0; fr < 2; ++fr) {
        int ai = ((k0 >> 3) + kch) * LSTR + wr2 + fr * 16 + lrow;
        ah[fr].u = xh_[ai]; al[fr].u = xl_[ai];
      }
#pragma unroll
      for (int fc = 0; fc < 2; ++fc) {
        size_t bi = (size_t)(((wc2 >> 4) + fc) * KCD + (k0 >> 3) + kch) * 128 + lrow * 8;
        bh[fc].u = *(const u32x4*)(P2h + bi);
        bl[fc].u = *(const u32x4*)(P2l + bi);
      }
#pragma unroll
      for (int fr = 0; fr < 2; ++fr)
#pragma unroll
        for (int fc = 0; fc < 2; ++fc) {
          pac[fr][fc] = __builtin_amdgcn_mfma_f32_16x16x32_bf16(ah[fr].s, bh[fc].s, pac[fr][fc], 0, 0, 0);
          pac[fr][fc] = __builtin_amdgcn_mfma_f32_16x16x32_bf16(al[fr].s, bh[fc].s, pac[fr][fc], 0, 0, 0);
          pac[fr][fc] = __builtin_amdgcn_mfma_f32_16x16x32_bf16(ah[fr].s, bl[fc].s, pac[fr][fc], 0, 0, 0);
        }
    }
#pragma unroll
    for (int fr = 0; fr < 2; ++fr)
#pragma unroll
      for (int fc = 0; fc < 2; ++fc) {
        pe_r[fr][fc] = pac[fr][fc];
#pragma unroll
        for (int q = 0; q < 4; ++q) {
          int row = wr2 + fr * 16 + kch * 4 + q;
          int col = wc2 + fc * 16 + lrow;
          float sv = pac[fr][fc][q] + u_r[fr][fc][q];
          u16 hi = f2bf(sv), lo = f2bf(sv - bf2f(hi));
          int off = ((col >> 3) * LSTR + row) * 8 + (col & 7);
          sh_u[off] = hi; sl_u[off] = lo;
        }
      }
  }
  __syncthreads();

  const int wra = (w / WCa) * 32, wca = (w % WCa) * 32;
  f32x4v lac[2][2];
#pragma unroll
  for (int a = 0; a < 2; ++a)
#pragma unroll
    for (int b = 0; b < 2; ++b) lac[a][b] = (f32x4v){0.f, 0.f, 0.f, 0.f};

#pragma unroll 1
  for (int it = 0; it < NIT; ++it) {
    const int hbase = it * HT;
    f32x4v aac[2][2];
#pragma unroll
    for (int a = 0; a < 2; ++a)
#pragma unroll
      for (int b = 0; b < 2; ++b) aac[a][b] = (f32x4v){0.f, 0.f, 0.f, 0.f};
#pragma unroll
    for (int k0 = 0; k0 < D; k0 += 32) {
      union { u32x4 u; short8 s; } ah[2], al[2], bh[2], bl[2];
#pragma unroll
      for (int fr = 0; fr < 2; ++fr) {
        int ai = ((k0 >> 3) + kch) * LSTR + wra + fr * 16 + lrow;
        ah[fr].u = sh_[ai]; al[fr].u = sl_[ai];
      }
#pragma unroll
      for (int fc = 0; fc < 2; ++fc) {
        size_t bi = (size_t)((((hbase + wca) >> 4) + fc) * KCD + (k0 >> 3) + kch) * 128 + lrow * 8;
        bh[fc].u = *(const u32x4*)(A1h + bi);
        bl[fc].u = *(const u32x4*)(A1l + bi);
      }
#pragma unroll
      for (int fr = 0; fr < 2; ++fr)
#pragma unroll
        for (int fc = 0; fc < 2; ++fc) {
          aac[fr][fc] = __builtin_amdgcn_mfma_f32_16x16x32_bf16(ah[fr].s, bh[fc].s, aac[fr][fc], 0, 0, 0);
          aac[fr][fc] = __builtin_amdgcn_mfma_f32_16x16x32_bf16(al[fr].s, bh[fc].s, aac[fr][fc], 0, 0, 0);
          aac[fr][fc] = __builtin_amdgcn_mfma_f32_16x16x32_bf16(ah[fr].s, bl[fc].s, aac[fr][fc], 0, 0, 0);
        }
    }
    __syncthreads();
#pragma unroll
    for (int fr = 0; fr < 2; ++fr)
#pragma unroll
      for (int fc = 0; fc < 2; ++fc)
#pragma unroll
        for (int q = 0; q < 4; ++q) {
          int row = wra + fr * 16 + kch * 4 + q;
          int ch = wca + fc * 16 + lrow;
          float av = fmaxf(aac[fr][fc][q], 0.f);
          u16 hi = f2bf(av), lo = f2bf(av - bf2f(hi));
          int off = ((ch >> 3) * LSTR + row) * 8 + (ch & 7);
          xh_u[off] = hi; xl_u[off] = lo;
        }
    __syncthreads();
#pragma unroll
    for (int k0 = 0; k0 < HT; k0 += 32) {
      union { u32x4 u; short8 s; } ah[2], al[2], bh[2], bl[2];
#pragma unroll
      for (int fr = 0; fr < 2; ++fr) {
        int ai = ((k0 >> 3) + kch) * LSTR + wr2 + fr * 16 + lrow;
        ah[fr].u = xh_[ai]; al[fr].u = xl_[ai];
      }
#pragma unroll
      for (int fc = 0; fc < 2; ++fc) {
        size_t bi = (size_t)(((wc2 >> 4) + fc) * KCH + ((hbase + k0) >> 3) + kch) * 128 + lrow * 8;
        bh[fc].u = *(const u32x4*)(A2h + bi);
        bl[fc].u = *(const u32x4*)(A2l + bi);
      }
#pragma unroll
      for (int fr = 0; fr < 2; ++fr)
#pragma unroll
        for (int fc = 0; fc < 2; ++fc) {
          lac[fr][fc] = __builtin_amdgcn_mfma_f32_16x16x32_bf16(ah[fr].s, bh[fc].s, lac[fr][fc], 0, 0, 0);
          lac[fr][fc] = __builtin_amdgcn_mfma_f32_16x16x32_bf16(al[fr].s, bh[fc].s, lac[fr][fc], 0, 0, 0);
          lac[fr][fc] = __builtin_amdgcn_mfma_f32_16x16x32_bf16(ah[fr].s, bl[fc].s, lac[fr][fc], 0, 0, 0);
        }
    }
  }

#pragma unroll
  for (int fr = 0; fr < 2; ++fr) {
    const int bmg = bm0 + ((wr2 + fr * 16) >> 4);
#pragma unroll
    for (int fc = 0; fc < 2; ++fc) {
      const int col = wc2 + fc * 16 + lrow;
      float lv[4];
#pragma unroll
      for (int q = 0; q < 4; ++q) lv[q] = lac[fr][fc][q];
      float mx = fmaxf(fmaxf(lv[0], lv[1]), fmaxf(lv[2], lv[3]));
      mx = fmaxf(mx, __shfl_xor(mx, 16));
      mx = fmaxf(mx, __shfl_xor(mx, 32));
      float ev[4];
      float ssum = 0.f;
#pragma unroll
      for (int q = 0; q < 4; ++q) { ev[q] = expf(lv[q] - mx); ssum += ev[q]; }
      ssum += __shfl_xor(ssum, 16);
      ssum += __shfl_xor(ssum, 32);
      float acc = 0.f;
#pragma unroll
      for (int q = 0; q < 4; ++q) {
        int row = wr2 + fr * 16 + kch * 4 + q;
        int np = nps[row];
        float vv = PC[(size_t)np * FD + 2 * D + col] + PC[(size_t)bmg * FD + 3 * D + col];
        acc += ev[q] * (vv + pe_r[fr][fc][q]);
      }
      acc += __shfl_xor(acc, 16);
      acc += __shfl_xor(acc, 32);
      if (kch == 0) xout[(size_t)bmg * D + col] = acc / ssum;
    }
  }
}

// ---------------------------------------------------------------------------
__global__ __launch_bounds__(256) void final_kernel(const float* __restrict__ x1,
                                                    const float* __restrict__ x2,
                                                    const float* __restrict__ x3,
                                                    float* __restrict__ out) {
  const int b = blockIdx.x, c = threadIdx.x;
  const float* p;
  int D, dc;
  if (c < 64)        { p = x1 + (size_t)b * M_ * 64;  D = 64;  dc = c; }
  else if (c < 128)  { p = x2 + (size_t)b * M_ * 64;  D = 64;  dc = c - 64; }
  else               { p = x3 + (size_t)b * M_ * 128; D = 128; dc = c - 128; }
  float mx = -__builtin_inff(), sm = 0.f;
#pragma unroll 8
  for (int m = 0; m < M_; ++m) {
    float v = p[(size_t)m * D + dc];
    mx = fmaxf(mx, v);
    sm += v;
  }
  out[(size_t)b * 512 + c] = mx;
  out[(size_t)b * 512 + 256 + c] = sm * (1.f / 512.f);
}

// ---------------------------------------------------------------------------
extern "C" void kernel_launch(void* const* d_in, const int* in_sizes, int n_in,
                              void* d_out, int out_size, void* d_ws, size_t ws_size,
                              hipStream_t stream) {
  const float* x = (const float*)d_in[0];
  const float* W[21];
  for (int i = 0; i < 21; ++i) W[i] = (const float*)d_in[1 + i];

  float* ws = (float*)d_ws;
  size_t off = 0;
  auto alloc = [&](size_t nfloats) { float* p = ws + off; off += nfloats; return p; };

  float* pts = alloc(24592);
  float* x1  = alloc((size_t)P_ * 64);
  float* x2  = alloc((size_t)P_ * 64);
  float* x3  = alloc((size_t)P_ * 128);
  int*   idxb = (int*)alloc((size_t)P_ * KNB);
  float* PC  = alloc((size_t)P_ * 512);    // [P][4D_max] f32
  u16* P2h = (u16*)alloc(8192);   u16* P2l = (u16*)alloc(8192);
  u16* A1h = (u16*)alloc(32768);  u16* A1l = (u16*)alloc(32768);
  u16* A2h = (u16*)alloc(32768);  u16* A2l = (u16*)alloc(32768);
  u16* WCh = (u16*)alloc(16384);  u16* WCl = (u16*)alloc(16384);

  fps_kernel<<<B_, 512, 0, stream>>>(x, pts);

  struct Layer {
    const float* f; int C, K32, D, H;
    const float *Wq, *Wk, *Wv, *P1, *P2, *A1, *A2;
    float* xout;
  };
  Layer ls[3] = {
      {pts, 3, 32, 64, 256, W[0], W[1], W[2], W[3], W[4], W[5], W[6], x1},
      {x1, 64, 64, 64, 256, W[7], W[8], W[9], W[10], W[11], W[12], W[13], x2},
      {x2, 64, 64, 128, 512, W[14], W[15], W[16], W[17], W[18], W[19], W[20], x3},
  };

  for (int li = 0; li < 3; ++li) {
    const Layer& L = ls[li];
    if (L.C == 3) knn_kernel<3><<<B_ * 16, 256, 0, stream>>>(L.f, idxb);
    else          knn_kernel<64><<<B_ * 16, 256, 0, stream>>>(L.f, idxb);

    int nW = 4 * L.D * L.K32;
    prep_wqkv<<<(nW + 255) / 256, 256, 0, stream>>>(
        L.Wq, L.Wk, L.Wv, L.C, L.D, L.K32, WCh, WCl);

    dim3 gPP(P_ / 64, 4 * L.D / 64);
    if (L.K32 == 32)
      pointproj_mfma<32><<<gPP, 256, 0, stream>>>(L.f, L.C, 4 * L.D, WCh, WCl, PC);
    else
      pointproj_mfma<64><<<gPP, 256, 0, stream>>>(L.f, L.C, 4 * L.D, WCh, WCl, PC);

    int nP2 = L.D * L.D, nA1 = L.H * L.D, nA2 = L.D * L.H;
    split3_w<<<(nP2 + nA1 + nA2 + 255) / 256, 256, 0, stream>>>(
        L.P2, nP2, L.D, L.A1, nA1, L.D, L.A2, nA2, L.H,
        P2h, P2l, A1h, A1l, A2h, A2l);

    if (L.D == 64)
      mega_kernel<64, 256, 64><<<ROWS_ / 64, 256, 0, stream>>>(
          pts, PC, idxb, L.P1, P2h, P2l, A1h, A1l, A2h, A2l, L.xout);
    else
      mega_kernel<128, 512, 32><<<ROWS_ / 32, 256, 0, stream>>>(
          pts, PC, idxb, L.P1, P2h, P2l, A1h, A1l, A2h, A2l, L.xout);
  }

  final_kernel<<<B_, 256, 0, stream>>>(x1, x2, x3, (float*)d_out);
}

// Round 20
// 996.366 us; speedup vs baseline: 1.0565x; 1.0565x over previous
//
#include <hip/hip_runtime.h>
#include <cstdint>
#include <cstddef>

#define B_  16
#define N_  4096
#define M_  512
#define KNB 16
#define P_  (B_ * M_)
#define ROWS_ (B_ * M_ * KNB)   // 131072

typedef unsigned short u16;
typedef unsigned long long u64;
typedef __attribute__((ext_vector_type(4))) unsigned int u32x4;
typedef __attribute__((ext_vector_type(8))) short short8;
typedef __attribute__((ext_vector_type(4))) float f32x4v;

__device__ inline u16 f2bf(float f) {
  union { float f; unsigned u; } x; x.f = f;
  unsigned r = x.u + 0x7fffu + ((x.u >> 16) & 1u);
  return (u16)(r >> 16);
}
__device__ inline float bf2f(u16 h) {
  union { unsigned u; float f; } x; x.u = ((unsigned)h) << 16;
  return x.f;
}

// ---------------------------------------------------------------------------
// Packed-u64 wave reductions via DPP (row_shr 1/2/4/8 + row_bcast 15/31).
// ---------------------------------------------------------------------------
__device__ inline u64 wave_max_u64(u64 k) {
#define STEP64MAX(ctrl)                                                               \
  {                                                                                   \
    unsigned olo = (unsigned)__builtin_amdgcn_update_dpp(0, (int)(unsigned)k, ctrl, 0xf, 0xf, false); \
    unsigned ohi = (unsigned)__builtin_amdgcn_update_dpp(0, (int)(unsigned)(k >> 32), ctrl, 0xf, 0xf, false); \
    u64 o = ((u64)ohi << 32) | olo;                                                   \
    k = o > k ? o : k;                                                                \
  }
  STEP64MAX(0x111) STEP64MAX(0x112) STEP64MAX(0x114) STEP64MAX(0x118)
  STEP64MAX(0x142) STEP64MAX(0x143)
#undef STEP64MAX
  unsigned rlo = (unsigned)__builtin_amdgcn_readlane((int)(unsigned)k, 63);
  unsigned rhi = (unsigned)__builtin_amdgcn_readlane((int)(unsigned)(k >> 32), 63);
  return ((u64)rhi << 32) | rlo;
}
__device__ inline u64 wave_min_u64(u64 k) {
#define STEP64MIN(ctrl)                                                               \
  {                                                                                   \
    unsigned olo = (unsigned)__builtin_amdgcn_update_dpp(-1, (int)(unsigned)k, ctrl, 0xf, 0xf, false); \
    unsigned ohi = (unsigned)__builtin_amdgcn_update_dpp(-1, (int)(unsigned)(k >> 32), ctrl, 0xf, 0xf, false); \
    u64 o = ((u64)ohi << 32) | olo;                                                   \
    k = o < k ? o : k;                                                                \
  }
  STEP64MIN(0x111) STEP64MIN(0x112) STEP64MIN(0x114) STEP64MIN(0x118)
  STEP64MIN(0x142) STEP64MIN(0x143)
#undef STEP64MIN
  unsigned rlo = (unsigned)__builtin_amdgcn_readlane((int)(unsigned)k, 63);
  unsigned rhi = (unsigned)__builtin_amdgcn_readlane((int)(unsigned)(k >> 32), 63);
  return ((u64)rhi << 32) | rlo;
}

// ---------------------------------------------------------------------------
// FPS (r18-verified BEST, 320us): 256 threads (4 waves), 16 pts/lane,
// packed-u64 key argmax. Distance chain bit-identical to the verified one.
// ---------------------------------------------------------------------------
__global__ __launch_bounds__(256) void fps_kernel(const float* __restrict__ x,
                                                  float* __restrict__ pts) {
  __shared__ float4 xs4[N_];
  __shared__ __align__(16) u64 rv64[2][4];
  const int b = blockIdx.x, t = threadIdx.x, lane = t & 63, w = t >> 6;
  const float* xb = x + (size_t)b * N_ * 3;
  for (int p = t; p < N_; p += 256) {
    const float* s = xb + p * 3;
    xs4[p] = make_float4(s[0], s[1], s[2], 0.f);
  }
  __syncthreads();

  float px[16], py[16], pz[16], dm[16];
#pragma unroll
  for (int j = 0; j < 16; ++j) {
    float4 v = xs4[t + j * 256];
    px[j] = v.x; py[j] = v.y; pz[j] = v.z;
    dm[j] = __builtin_inff();
  }
  float cx = xs4[0].x, cy = xs4[0].y, cz = xs4[0].z;
  if (t == 0) {
    pts[(size_t)b * M_ * 3 + 0] = cx;
    pts[(size_t)b * M_ * 3 + 1] = cy;
    pts[(size_t)b * M_ * 3 + 2] = cz;
  }
  for (int i = 1; i < M_; ++i) {
    u64 kk[16];
#pragma unroll
    for (int j = 0; j < 16; ++j) {
      float dx = px[j] - cx, dy = py[j] - cy, dz = pz[j] - cz;
      float dd = __fmul_rn(dx, dx);
      dd = __fadd_rn(dd, __fmul_rn(dy, dy));
      dd = __fadd_rn(dd, __fmul_rn(dz, dz));
      dd = fminf(dm[j], dd);
      dm[j] = dd;
      kk[j] = ((u64)__float_as_uint(dd) << 32) | (unsigned)(~(t + j * 256));
    }
    u64 k8[8], k4[4], k2[2], kb;
#pragma unroll
    for (int j = 0; j < 8; ++j) k8[j] = kk[j] > kk[j + 8] ? kk[j] : kk[j + 8];
#pragma unroll
    for (int j = 0; j < 4; ++j) k4[j] = k8[j] > k8[j + 4] ? k8[j] : k8[j + 4];
#pragma unroll
    for (int j = 0; j < 2; ++j) k2[j] = k4[j] > k4[j + 2] ? k4[j] : k4[j + 2];
    kb = k2[0] > k2[1] ? k2[0] : k2[1];
    kb = wave_max_u64(kb);

    const int par = i & 1;
    if (lane == 0) rv64[par][w] = kb;
    __syncthreads();
    u32x4 a0 = *(const u32x4*)&rv64[par][0];   // keys 0,1
    u32x4 a1 = *(const u32x4*)&rv64[par][2];   // keys 2,3
    u64 q0 = ((u64)a0[1] << 32) | a0[0];
    u64 q1 = ((u64)a0[3] << 32) | a0[2];
    u64 q2 = ((u64)a1[1] << 32) | a1[0];
    u64 q3 = ((u64)a1[3] << 32) | a1[2];
    u64 m0 = q0 > q1 ? q0 : q1;
    u64 m1 = q2 > q3 ? q2 : q3;
    u64 km = m0 > m1 ? m0 : m1;
    int fi = (int)(~(unsigned)km) & (N_ - 1);
    float4 cc = xs4[fi];
    cx = cc.x; cy = cc.y; cz = cc.z;
    if (t == 0) {
      pts[((size_t)b * M_ + i) * 3 + 0] = cx;
      pts[((size_t)b * M_ + i) * 3 + 1] = cy;
      pts[((size_t)b * M_ + i) * 3 + 2] = cz;
    }
  }
}

// ---------------------------------------------------------------------------
// kNN (r13-verified): 256 threads, ~252 VGPRs, keyed top-16, equality
// invalidation with compile-time indices (no scratch spill).
// ---------------------------------------------------------------------------
template <int C>
__global__ __launch_bounds__(256) void knn_kernel(const float* __restrict__ f,
                                                  int* __restrict__ knn) {
  constexpr int C4 = (C + 3) / 4;
  __shared__ float4 ls4[C4 * 513];
  float* lss = (float*)ls4;
  const int b = blockIdx.x >> 4;
  const int mb = (blockIdx.x & 15) * 32;
  const int t = threadIdx.x, lane = t & 63, w = t >> 6;
  const float* fb = f + (size_t)b * M_ * C;
  if (C & 3) {
    for (int j = t; j < M_; j += 256)
      for (int cc = (C & 3); cc < 4; ++cc)
        lss[((C4 - 1) * 513 + j) * 4 + cc] = 0.f;
  }
  for (int s = t; s < M_ * C; s += 256) {
    int j = s / C, c = s % C;
    lss[((c >> 2) * 513 + j) * 4 + (c & 3)] = fb[s];
  }
  __syncthreads();

  float sqj[8];
#pragma unroll
  for (int jj = 0; jj < 8; ++jj) {
    int j = lane + 64 * jj;
    float a = 0.f;
    for (int c4 = 0; c4 < C4; ++c4) {
      float4 v = ls4[c4 * 513 + j];
      a += v.x * v.x + v.y * v.y + v.z * v.z + v.w * v.w;
    }
    sqj[jj] = a;
  }

  for (int rr = 0; rr < 8; ++rr) {
    const int m = mb + w * 8 + rr;
    float sqm = 0.f;
    for (int c4 = 0; c4 < C4; ++c4) {
      float4 v = ls4[c4 * 513 + m];
      sqm += v.x * v.x + v.y * v.y + v.z * v.z + v.w * v.w;
    }
    float dot[8] = {0.f, 0.f, 0.f, 0.f, 0.f, 0.f, 0.f, 0.f};
    for (int c4 = 0; c4 < C4; ++c4) {
      float4 fm = ls4[c4 * 513 + m];
#pragma unroll
      for (int jj = 0; jj < 8; ++jj) {
        float4 fj = ls4[c4 * 513 + lane + 64 * jj];
        dot[jj] += fm.x * fj.x + fm.y * fj.y + fm.z * fj.z + fm.w * fj.w;
      }
    }
    u64 mk[8];
#pragma unroll
    for (int jj = 0; jj < 8; ++jj) {
      float d = (sqm - 2.f * dot[jj]) + sqj[jj];
      unsigned um = __float_as_uint(d);
      um = (um >> 31) ? ~um : (um | 0x80000000u);   // order-preserving f32->u32
      mk[jj] = ((u64)um << 32) | (unsigned)(lane + 64 * jj);
    }

    int* out = knn + ((size_t)b * M_ + m) * KNB;
    for (int kk = 0; kk < KNB; ++kk) {
      u64 k4[4], k2[2], kb;
#pragma unroll
      for (int jj = 0; jj < 4; ++jj) k4[jj] = mk[jj] < mk[jj + 4] ? mk[jj] : mk[jj + 4];
#pragma unroll
      for (int jj = 0; jj < 2; ++jj) k2[jj] = k4[jj] < k4[jj + 2] ? k4[jj] : k4[jj + 2];
      kb = k2[0] < k2[1] ? k2[0] : k2[1];
      kb = wave_min_u64(kb);
#pragma unroll
      for (int jj = 0; jj < 8; ++jj)
        if (mk[jj] == kb) mk[jj] = ~0ull;          // unique keys -> exact winner
      if (lane == 0) out[kk] = (int)(unsigned)kb;
    }
  }
}

// ---------------------------------------------------------------------------
// Weight prep for pointproj (r17-verified): Wcomb[4D][K32] hi/lo, swizzled.
// ---------------------------------------------------------------------------
__global__ void prep_wqkv(const float* __restrict__ Wq, const float* __restrict__ Wk,
                          const float* __restrict__ Wv, int C, int D, int K32,
                          u16* __restrict__ Wh, u16* __restrict__ Wl) {
  int idx = blockIdx.x * 256 + threadIdx.x;
  if (idx >= 4 * D * K32) return;
  int n = idx / K32, c = idx % K32;
  float wv = 0.f;
  if (c < C) {
    int reg = n / D, d = n % D;
    int twoC = 2 * C;
    if (reg == 0)      wv = Wq[d * twoC + c] - Wk[d * twoC + c];
    else if (reg == 1) wv = (Wq[d * twoC + C + c] - Wk[d * twoC + C + c]) -
                            (Wq[d * twoC + c] - Wk[d * twoC + c]);
    else if (reg == 2) wv = Wv[d * twoC + c];
    else               wv = Wv[d * twoC + C + c] - Wv[d * twoC + c];
  }
  int sw = ((n >> 4) * (K32 >> 3) + (c >> 3)) * 128 + (n & 15) * 8 + (c & 7);
  u16 h = f2bf(wv);
  Wh[sw] = h;
  Wl[sw] = f2bf(wv - bf2f(h));
}

// ---------------------------------------------------------------------------
// pointproj via split-precision MFMA (r17-verified).
// ---------------------------------------------------------------------------
template <int K32>
__global__ __launch_bounds__(256) void pointproj_mfma(
    const float* __restrict__ f, int C, int fourD,
    const u16* __restrict__ Wh, const u16* __restrict__ Wl,
    float* __restrict__ PC) {
  __shared__ u32x4 Ah[4 * 65], Al[4 * 65];
  constexpr int KC = K32 / 8;
  const int t = threadIdx.x, lane = t & 63, w = t >> 6;
  const int r0 = blockIdx.x * 64, n0 = blockIdx.y * 64;
  const int wr = (w >> 1) * 32, wc = (w & 1) * 32;
  const int kch = lane >> 4, lrow = lane & 15;
  const int srow = t >> 2, ss = t & 3;
  f32x4v acc[2][2];
#pragma unroll
  for (int a = 0; a < 2; ++a)
#pragma unroll
    for (int b = 0; b < 2; ++b) acc[a][b] = (f32x4v){0.f, 0.f, 0.f, 0.f};

  const int ldsw = ss * 65 + srow;
  const int ra = kch * 65 + lrow;

#pragma unroll
  for (int k0 = 0; k0 < K32; k0 += 32) {
    float af[8];
#pragma unroll
    for (int i = 0; i < 8; ++i) {
      int c = k0 + ss * 8 + i;
      af[i] = (c < C) ? f[(size_t)(r0 + srow) * C + c] : 0.f;
    }
    u32x4 vah, val;
#pragma unroll
    for (int q = 0; q < 4; ++q) {
      u16 h0 = f2bf(af[2 * q]), h1 = f2bf(af[2 * q + 1]);
      u16 l0 = f2bf(af[2 * q] - bf2f(h0));
      u16 l1 = f2bf(af[2 * q + 1] - bf2f(h1));
      vah[q] = (unsigned)h0 | ((unsigned)h1 << 16);
      val[q] = (unsigned)l0 | ((unsigned)l1 << 16);
    }
    __syncthreads();
    Ah[ldsw] = vah; Al[ldsw] = val;
    __syncthreads();
    union { u32x4 u; short8 s; } ah0, ah1, al0, al1, bh[2], bl[2];
    ah0.u = Ah[ra + wr]; ah1.u = Ah[ra + wr + 16];
    al0.u = Al[ra + wr]; al1.u = Al[ra + wr + 16];
#pragma unroll
    for (int fc = 0; fc < 2; ++fc) {
      size_t bi = (size_t)((((n0 + wc) >> 4) + fc) * KC + (k0 >> 3) + kch) * 128 + lrow * 8;
      bh[fc].u = *(const u32x4*)(Wh + bi);
      bl[fc].u = *(const u32x4*)(Wl + bi);
    }
#pragma unroll
    for (int fc = 0; fc < 2; ++fc) {
      acc[0][fc] = __builtin_amdgcn_mfma_f32_16x16x32_bf16(ah0.s, bh[fc].s, acc[0][fc], 0, 0, 0);
      acc[1][fc] = __builtin_amdgcn_mfma_f32_16x16x32_bf16(ah1.s, bh[fc].s, acc[1][fc], 0, 0, 0);
      acc[0][fc] = __builtin_amdgcn_mfma_f32_16x16x32_bf16(al0.s, bh[fc].s, acc[0][fc], 0, 0, 0);
      acc[1][fc] = __builtin_amdgcn_mfma_f32_16x16x32_bf16(al1.s, bh[fc].s, acc[1][fc], 0, 0, 0);
      acc[0][fc] = __builtin_amdgcn_mfma_f32_16x16x32_bf16(ah0.s, bl[fc].s, acc[0][fc], 0, 0, 0);
      acc[1][fc] = __builtin_amdgcn_mfma_f32_16x16x32_bf16(ah1.s, bl[fc].s, acc[1][fc], 0, 0, 0);
    }
  }

  const int rowb = r0 + wr + kch * 4;
  const int colb = n0 + wc + lrow;
#pragma unroll
  for (int fr = 0; fr < 2; ++fr)
#pragma unroll
    for (int fc = 0; fc < 2; ++fc)
#pragma unroll
      for (int q = 0; q < 4; ++q) {
        int row = rowb + fr * 16 + q;
        int col = colb + fc * 16;
        PC[(size_t)row * fourD + col] = acc[fr][fc][q];
      }
}

// ---------------------------------------------------------------------------
// Weight split + swizzle to MFMA fragment order (P2/A1/A2).
// ---------------------------------------------------------------------------
__global__ void split3_w(const float* __restrict__ Wa, int na, int Ka,
                         const float* __restrict__ Wb, int nb, int Kb,
                         const float* __restrict__ Wc, int nc, int Kc,
                         u16* __restrict__ Ah, u16* __restrict__ Al,
                         u16* __restrict__ Bh, u16* __restrict__ Bl,
                         u16* __restrict__ Ch, u16* __restrict__ Cl) {
  int k = blockIdx.x * 256 + threadIdx.x;
  const float* s; u16 *dh, *dl; int K;
  if (k < na) { s = Wa; dh = Ah; dl = Al; K = Ka; }
  else if ((k -= na) < nb) { s = Wb; dh = Bh; dl = Bl; K = Kb; }
  else if ((k -= nb) < nc) { s = Wc; dh = Ch; dl = Cl; K = Kc; }
  else return;
  int n = k / K, kk = k % K;
  int sw = ((n >> 4) * (K >> 3) + (kk >> 3)) * 128 + (n & 15) * 8 + (kk & 7);
  float v = s[k];
  u16 h = f2bf(v);
  dh[sw] = h;
  dl[sw] = f2bf(v - bf2f(h));
}

// ---------------------------------------------------------------------------
// Fused transformer layer (r15-verified: swizzled weight fragments).
// ---------------------------------------------------------------------------
template <int D, int H, int RB>
__global__ __launch_bounds__(256) void mega_kernel(
    const float* __restrict__ pts, const float* __restrict__ PC,
    const int* __restrict__ idx, const float* __restrict__ P1,
    const u16* __restrict__ P2h, const u16* __restrict__ P2l,
    const u16* __restrict__ A1h, const u16* __restrict__ A1l,
    const u16* __restrict__ A2h, const u16* __restrict__ A2l,
    float* __restrict__ xout) {
  constexpr int WC = D / 32;
  constexpr int HT = (RB == 64) ? 64 : 128;
  constexpr int WCa = HT / 32;
  constexpr int KCD = D / 8;
  constexpr int KCH = H / 8;
  constexpr int NIT = H / HT;
  constexpr int LSTR = RB + 1;
  constexpr int FD = 4 * D;

  __shared__ u32x4 sh_[KCD * LSTR], sl_[KCD * LSTR];
  __shared__ u32x4 xh_[KCD * LSTR], xl_[KCD * LSTR];
  __shared__ float rel4[RB][4];
  __shared__ int   nps[RB];
  __shared__ float P1s[D][4];

  const int t = threadIdx.x, lane = t & 63, w = t >> 6;
  const int kch = lane >> 4, lrow = lane & 15;
  const int r0g = blockIdx.x * RB;
  const int bm0 = r0g >> 4;

  if (t < RB) {
    int gr = r0g + t;
    int bb = gr >> 13;
    int np = bb * M_ + idx[gr];
    int bm = gr >> 4;
    nps[t] = np;
    rel4[t][0] = pts[np * 3 + 0] - pts[bm * 3 + 0];
    rel4[t][1] = pts[np * 3 + 1] - pts[bm * 3 + 1];
    rel4[t][2] = pts[np * 3 + 2] - pts[bm * 3 + 2];
  }
  for (int e = t; e < D * 4; e += 256) {
    int dd = e >> 2, c = e & 3;
    P1s[dd][c] = (c < 3) ? P1[dd * 3 + c] : 0.f;
  }
  __syncthreads();

  u16* xh_u = (u16*)xh_;
  u16* xl_u = (u16*)xl_;
  u16* sh_u = (u16*)sh_;
  u16* sl_u = (u16*)sl_;

  const int wr2 = (w / WC) * 32, wc2 = (w % WC) * 32;

  // u gathered per-fragment into registers
  float u_r[2][2][4];
#pragma unroll
  for (int fr = 0; fr < 2; ++fr)
#pragma unroll
    for (int fc = 0; fc < 2; ++fc)
#pragma unroll
      for (int q = 0; q < 4; ++q) {
        int row = wr2 + fr * 16 + kch * 4 + q;
        int col = wc2 + fc * 16 + lrow;
        int np = nps[row];
        int bm = bm0 + (row >> 4);
        u_r[fr][fc][q] = PC[(size_t)np * FD + col] + PC[(size_t)bm * FD + D + col];
      }

  // h1 build (bf16 hi/lo into LDS)
#pragma unroll
  for (int i = 0; i < RB * D / 256; ++i) {
    int e = t + i * 256;
    int r = e / D, dd = e % D;
    float hh = fmaxf(P1s[dd][0] * rel4[r][0] + P1s[dd][1] * rel4[r][1] +
                     P1s[dd][2] * rel4[r][2], 0.f);
    u16 hi = f2bf(hh), lo = f2bf(hh - bf2f(hi));
    int off = ((dd >> 3) * LSTR + r) * 8 + (dd & 7);
    xh_u[off] = hi; xl_u[off] = lo;
  }
  __syncthreads();

  // phase 2: pe = h1 @ P2^T ; s = u + pe ; pe kept in registers
  f32x4v pe_r[2][2];
  {
    f32x4v pac[2][2];
#pragma unroll
    for (int a = 0; a < 2; ++a)
#pragma unroll
      for (int b = 0; b < 2; ++b) pac[a][b] = (f32x4v){0.f, 0.f, 0.f, 0.f};
#pragma unroll
    for (int k0 = 0; k0 < D; k0 += 32) {
      union { u32x4 u; short8 s; } ah[2], al[2], bh[2], bl[2];
#pragma unroll
      for (int fr = 0; fr < 2; ++fr) {
        int ai = ((k0 >> 3) + kch) * LSTR + wr2 + fr * 16 + lrow;
        ah[fr].u = xh_[ai]; al[fr].u = xl_[ai];
      }
#pragma unroll
      for (int fc = 0; fc < 2; ++fc) {
        size_t bi = (size_t)(((wc2 >> 4) + fc) * KCD + (k0 >> 3) + kch) * 128 + lrow * 8;
        bh[fc].u = *(const u32x4*)(P2h + bi);
        bl[fc].u = *(const u32x4*)(P2l + bi);
      }
#pragma unroll
      for (int fr = 0; fr < 2; ++fr)
#pragma unroll
        for (int fc = 0; fc < 2; ++fc) {
          pac[fr][fc] = __builtin_amdgcn_mfma_f32_16x16x32_bf16(ah[fr].s, bh[fc].s, pac[fr][fc], 0, 0, 0);
          pac[fr][fc] = __builtin_amdgcn_mfma_f32_16x16x32_bf16(al[fr].s, bh[fc].s, pac[fr][fc], 0, 0, 0);
          pac[fr][fc] = __builtin_amdgcn_mfma_f32_16x16x32_bf16(ah[fr].s, bl[fc].s, pac[fr][fc], 0, 0, 0);
        }
    }
#pragma unroll
    for (int fr = 0; fr < 2; ++fr)
#pragma unroll
      for (int fc = 0; fc < 2; ++fc) {
        pe_r[fr][fc] = pac[fr][fc];
#pragma unroll
        for (int q = 0; q < 4; ++q) {
          int row = wr2 + fr * 16 + kch * 4 + q;
          int col = wc2 + fc * 16 + lrow;
          float sv = pac[fr][fc][q] + u_r[fr][fc][q];
          u16 hi = f2bf(sv), lo = f2bf(sv - bf2f(hi));
          int off = ((col >> 3) * LSTR + row) * 8 + (col & 7);
          sh_u[off] = hi; sl_u[off] = lo;
        }
      }
  }
  __syncthreads();

  const int wra = (w / WCa) * 32, wca = (w % WCa) * 32;
  f32x4v lac[2][2];
#pragma unroll
  for (int a = 0; a < 2; ++a)
#pragma unroll
    for (int b = 0; b < 2; ++b) lac[a][b] = (f32x4v){0.f, 0.f, 0.f, 0.f};

#pragma unroll 1
  for (int it = 0; it < NIT; ++it) {
    const int hbase = it * HT;
    f32x4v aac[2][2];
#pragma unroll
    for (int a = 0; a < 2; ++a)
#pragma unroll
      for (int b = 0; b < 2; ++b) aac[a][b] = (f32x4v){0.f, 0.f, 0.f, 0.f};
#pragma unroll
    for (int k0 = 0; k0 < D; k0 += 32) {
      union { u32x4 u; short8 s; } ah[2], al[2], bh[2], bl[2];
#pragma unroll
      for (int fr = 0; fr < 2; ++fr) {
        int ai = ((k0 >> 3) + kch) * LSTR + wra + fr * 16 + lrow;
        ah[fr].u = sh_[ai]; al[fr].u = sl_[ai];
      }
#pragma unroll
      for (int fc = 0; fc < 2; ++fc) {
        size_t bi = (size_t)((((hbase + wca) >> 4) + fc) * KCD + (k0 >> 3) + kch) * 128 + lrow * 8;
        bh[fc].u = *(const u32x4*)(A1h + bi);
        bl[fc].u = *(const u32x4*)(A1l + bi);
      }
#pragma unroll
      for (int fr = 0; fr < 2; ++fr)
#pragma unroll
        for (int fc = 0; fc < 2; ++fc) {
          aac[fr][fc] = __builtin_amdgcn_mfma_f32_16x16x32_bf16(ah[fr].s, bh[fc].s, aac[fr][fc], 0, 0, 0);
          aac[fr][fc] = __builtin_amdgcn_mfma_f32_16x16x32_bf16(al[fr].s, bh[fc].s, aac[fr][fc], 0, 0, 0);
          aac[fr][fc] = __builtin_amdgcn_mfma_f32_16x16x32_bf16(ah[fr].s, bl[fc].s, aac[fr][fc], 0, 0, 0);
        }
    }
    __syncthreads();
#pragma unroll
    for (int fr = 0; fr < 2; ++fr)
#pragma unroll
      for (int fc = 0; fc < 2; ++fc)
#pragma unroll
        for (int q = 0; q < 4; ++q) {
          int row = wra + fr * 16 + kch * 4 + q;
          int ch = wca + fc * 16 + lrow;
          float av = fmaxf(aac[fr][fc][q], 0.f);
          u16 hi = f2bf(av), lo = f2bf(av - bf2f(hi));
          int off = ((ch >> 3) * LSTR + row) * 8 + (ch & 7);
          xh_u[off] = hi; xl_u[off] = lo;
        }
    __syncthreads();
#pragma unroll
    for (int k0 = 0; k0 < HT; k0 += 32) {
      union { u32x4 u; short8 s; } ah[2], al[2], bh[2], bl[2];
#pragma unroll
      for (int fr = 0; fr < 2; ++fr) {
        int ai = ((k0 >> 3) + kch) * LSTR + wr2 + fr * 16 + lrow;
        ah[fr].u = xh_[ai]; al[fr].u = xl_[ai];
      }
#pragma unroll
      for (int fc = 0; fc < 2; ++fc) {
        size_t bi = (size_t)(((wc2 >> 4) + fc) * KCH + ((hbase + k0) >> 3) + kch) * 128 + lrow * 8;
        bh[fc].u = *(const u32x4*)(A2h + bi);
        bl[fc].u = *(const u32x4*)(A2l + bi);
      }
#pragma unroll
      for (int fr = 0; fr < 2; ++fr)
#pragma unroll
        for (int fc = 0; fc < 2; ++fc) {
          lac[fr][fc] = __builtin_amdgcn_mfma_f32_16x16x32_bf16(ah[fr].s, bh[fc].s, lac[fr][fc], 0, 0, 0);
          lac[fr][fc] = __builtin_amdgcn_mfma_f32_16x16x32_bf16(al[fr].s, bh[fc].s, lac[fr][fc], 0, 0, 0);
          lac[fr][fc] = __builtin_amdgcn_mfma_f32_16x16x32_bf16(ah[fr].s, bl[fc].s, lac[fr][fc], 0, 0, 0);
        }
    }
  }

#pragma unroll
  for (int fr = 0; fr < 2; ++fr) {
    const int bmg = bm0 + ((wr2 + fr * 16) >> 4);
#pragma unroll
    for (int fc = 0; fc < 2; ++fc) {
      const int col = wc2 + fc * 16 + lrow;
      float lv[4];
#pragma unroll
      for (int q = 0; q < 4; ++q) lv[q] = lac[fr][fc][q];
      float mx = fmaxf(fmaxf(lv[0], lv[1]), fmaxf(lv[2], lv[3]));
      mx = fmaxf(mx, __shfl_xor(mx, 16));
      mx = fmaxf(mx, __shfl_xor(mx, 32));
      float ev[4];
      float ssum = 0.f;
#pragma unroll
      for (int q = 0; q < 4; ++q) { ev[q] = expf(lv[q] - mx); ssum += ev[q]; }
      ssum += __shfl_xor(ssum, 16);
      ssum += __shfl_xor(ssum, 32);
      float acc = 0.f;
#pragma unroll
      for (int q = 0; q < 4; ++q) {
        int row = wr2 + fr * 16 + kch * 4 + q;
        int np = nps[row];
        float vv = PC[(size_t)np * FD + 2 * D + col] + PC[(size_t)bmg * FD + 3 * D + col];
        acc += ev[q] * (vv + pe_r[fr][fc][q]);
      }
      acc += __shfl_xor(acc, 16);
      acc += __shfl_xor(acc, 32);
      if (kch == 0) xout[(size_t)bmg * D + col] = acc / ssum;
    }
  }
}

// ---------------------------------------------------------------------------
__global__ __launch_bounds__(256) void final_kernel(const float* __restrict__ x1,
                                                    const float* __restrict__ x2,
                                                    const float* __restrict__ x3,
                                                    float* __restrict__ out) {
  const int b = blockIdx.x, c = threadIdx.x;
  const float* p;
  int D, dc;
  if (c < 64)        { p = x1 + (size_t)b * M_ * 64;  D = 64;  dc = c; }
  else if (c < 128)  { p = x2 + (size_t)b * M_ * 64;  D = 64;  dc = c - 64; }
  else               { p = x3 + (size_t)b * M_ * 128; D = 128; dc = c - 128; }
  float mx = -__builtin_inff(), sm = 0.f;
#pragma unroll 8
  for (int m = 0; m < M_; ++m) {
    float v = p[(size_t)m * D + dc];
    mx = fmaxf(mx, v);
    sm += v;
  }
  out[(size_t)b * 512 + c] = mx;
  out[(size_t)b * 512 + 256 + c] = sm * (1.f / 512.f);
}

// ---------------------------------------------------------------------------
extern "C" void kernel_launch(void* const* d_in, const int* in_sizes, int n_in,
                              void* d_out, int out_size, void* d_ws, size_t ws_size,
                              hipStream_t stream) {
  const float* x = (const float*)d_in[0];
  const float* W[21];
  for (int i = 0; i < 21; ++i) W[i] = (const float*)d_in[1 + i];

  float* ws = (float*)d_ws;
  size_t off = 0;
  auto alloc = [&](size_t nfloats) { float* p = ws + off; off += nfloats; return p; };

  float* pts = alloc(24592);
  float* x1  = alloc((size_t)P_ * 64);
  float* x2  = alloc((size_t)P_ * 64);
  float* x3  = alloc((size_t)P_ * 128);
  int*   idxb = (int*)alloc((size_t)P_ * KNB);
  float* PC  = alloc((size_t)P_ * 512);    // [P][4D_max] f32
  u16* P2h = (u16*)alloc(8192);   u16* P2l = (u16*)alloc(8192);
  u16* A1h = (u16*)alloc(32768);  u16* A1l = (u16*)alloc(32768);
  u16* A2h = (u16*)alloc(32768);  u16* A2l = (u16*)alloc(32768);
  u16* WCh = (u16*)alloc(16384);  u16* WCl = (u16*)alloc(16384);

  fps_kernel<<<B_, 256, 0, stream>>>(x, pts);

  struct Layer {
    const float* f; int C, K32, D, H;
    const float *Wq, *Wk, *Wv, *P1, *P2, *A1, *A2;
    float* xout;
  };
  Layer ls[3] = {
      {pts, 3, 32, 64, 256, W[0], W[1], W[2], W[3], W[4], W[5], W[6], x1},
      {x1, 64, 64, 64, 256, W[7], W[8], W[9], W[10], W[11], W[12], W[13], x2},
      {x2, 64, 64, 128, 512, W[14], W[15], W[16], W[17], W[18], W[19], W[20], x3},
  };

  for (int li = 0; li < 3; ++li) {
    const Layer& L = ls[li];
    if (L.C == 3) knn_kernel<3><<<B_ * 16, 256, 0, stream>>>(L.f, idxb);
    else          knn_kernel<64><<<B_ * 16, 256, 0, stream>>>(L.f, idxb);

    int nW = 4 * L.D * L.K32;
    prep_wqkv<<<(nW + 255) / 256, 256, 0, stream>>>(
        L.Wq, L.Wk, L.Wv, L.C, L.D, L.K32, WCh, WCl);

    dim3 gPP(P_ / 64, 4 * L.D / 64);
    if (L.K32 == 32)
      pointproj_mfma<32><<<gPP, 256, 0, stream>>>(L.f, L.C, 4 * L.D, WCh, WCl, PC);
    else
      pointproj_mfma<64><<<gPP, 256, 0, stream>>>(L.f, L.C, 4 * L.D, WCh, WCl, PC);

    int nP2 = L.D * L.D, nA1 = L.H * L.D, nA2 = L.D * L.H;
    split3_w<<<(nP2 + nA1 + nA2 + 255) / 256, 256, 0, stream>>>(
        L.P2, nP2, L.D, L.A1, nA1, L.D, L.A2, nA2, L.H,
        P2h, P2l, A1h, A1l, A2h, A2l);

    if (L.D == 64)
      mega_kernel<64, 256, 64><<<ROWS_ / 64, 256, 0, stream>>>(
          pts, PC, idxb, L.P1, P2h, P2l, A1h, A1l, A2h, A2l, L.xout);
    else
      mega_kernel<128, 512, 32><<<ROWS_ / 32, 256, 0, stream>>>(
          pts, PC, idxb, L.P1, P2h, P2l, A1h, A1l, A2h, A2l, L.xout);
  }

  final_kernel<<<B_, 256, 0, stream>>>(x1, x2, x3, (float*)d_out);
}